// Round 9
// baseline (198.986 us; speedup 1.0000x reference)
//
#include <hip/hip_runtime.h>

// ---------------------------------------------------------------------------
// HSTU encoder layer, MI355X.  S=2048 B=2 E=1024 H=16 D=64, M = S*B = 4096.
// prep(cvt W + LN) -> GEMM BK=64 (in_proj,silu) -> attn v5 (4 blocks/CU,
//   single-buffer, q-subtiled pairs, bpermute transpose) -> GEMM BK=64 (out_proj)
// All matmuls: v_mfma_f32_16x16x32_bf16, f32 accum.
// ---------------------------------------------------------------------------

typedef __attribute__((ext_vector_type(8))) short  short8;   // 8 bf16 = 4 VGPR
typedef __attribute__((ext_vector_type(4))) float  floatx4;  // MFMA C/D frag
typedef __attribute__((ext_vector_type(4))) float  fvec4;
typedef __attribute__((ext_vector_type(4))) unsigned short usvec4;
typedef __attribute__((ext_vector_type(4))) int    intx4;

__device__ __forceinline__ unsigned short f2b(float f) {  // f32 -> bf16 RNE
  unsigned u = __builtin_bit_cast(unsigned, f);
  u += 0x7FFFu + ((u >> 16) & 1u);
  return (unsigned short)(u >> 16);
}
__device__ __forceinline__ float b2f(unsigned short h) {
  unsigned u = ((unsigned)h) << 16;
  return __builtin_bit_cast(float, u);
}
// silu via raw v_exp/v_rcp: x<<0 -> exp2(+inf)->rcp->0 OK; x>>0 -> 1*x OK.
__device__ __forceinline__ float silu_f(float x) {
  float e = __builtin_amdgcn_exp2f(-1.44269504f * x);
  return x * __builtin_amdgcn_rcpf(1.f + e);
}
__device__ __forceinline__ void async_copy16(void* lds, const void* g) {
  __builtin_amdgcn_global_load_lds(
      (__attribute__((address_space(1))) void*)(g),
      (__attribute__((address_space(3))) void*)(lds), 16, 0, 0);
}

// ---------------------------------------------------------------- prep:
// blocks [0,3072): cvt w1/w2 f32->bf16.  blocks [3072,4096): LayerNorm
// (one wave per row, shfl_xor reduce).
__global__ __launch_bounds__(256) void prep_kernel(
    const float* __restrict__ w1, unsigned short* __restrict__ w1b,
    const float* __restrict__ w2, unsigned short* __restrict__ w2b,
    const float* __restrict__ x, const float* __restrict__ g,
    const float* __restrict__ b, unsigned short* __restrict__ xn) {
  const int blk = blockIdx.x;
  if (blk < 3072) {
    int i = blk * 256 + threadIdx.x;      // over 786432 fvec4 groups
    const float* s; unsigned short* d; int j;
    if (i < 524288) { s = w1; d = w1b; j = i; } else { s = w2; d = w2b; j = i - 524288; }
    fvec4 v = ((const fvec4*)s)[j];
    usvec4 o = { f2b(v.x), f2b(v.y), f2b(v.z), f2b(v.w) };
    ((usvec4*)d)[j] = o;
    return;
  }
  const int lane = threadIdx.x & 63;
  const int row = (blk - 3072) * 4 + (threadIdx.x >> 6);
  const fvec4* xr = (const fvec4*)(x + (long)row * 1024);
  fvec4 v[4];
  float s = 0.f, s2 = 0.f;
  #pragma unroll
  for (int c = 0; c < 4; ++c) {
    v[c] = xr[lane + 64 * c];
    s  += v[c].x + v[c].y + v[c].z + v[c].w;
    s2 += v[c].x*v[c].x + v[c].y*v[c].y + v[c].z*v[c].z + v[c].w*v[c].w;
  }
  #pragma unroll
  for (int off = 32; off; off >>= 1) { s += __shfl_xor(s, off); s2 += __shfl_xor(s2, off); }
  float mu  = s * (1.f / 1024.f);
  float var = s2 * (1.f / 1024.f) - mu * mu;
  float rs  = rsqrtf(var + 1e-5f);
  usvec4* outr = (usvec4*)(xn + (long)row * 1024);
  #pragma unroll
  for (int c = 0; c < 4; ++c) {
    fvec4 gg = ((const fvec4*)g)[lane + 64 * c];
    fvec4 bb = ((const fvec4*)b)[lane + 64 * c];
    usvec4 o = { f2b((v[c].x - mu) * rs * gg.x + bb.x),
                 f2b((v[c].y - mu) * rs * gg.y + bb.y),
                 f2b((v[c].z - mu) * rs * gg.z + bb.z),
                 f2b((v[c].w - mu) * rs * gg.w + bb.w) };
    outr[lane + 64 * c] = o;
  }
}

// ---------------------------------------------------------------- GEMM in_proj
// C = A * Bw^T, 128x128 tile, BK=64 dual 32-wide sub-buffers. 16 K-iters.
// epilogue: v=silu(v+bias); n<1024 -> qkv else u (both [m][1024] bf16)
__global__ __launch_bounds__(256, 2) void gemm_in(
    const unsigned short* __restrict__ A, const unsigned short* __restrict__ Bw,
    const float* __restrict__ bias,
    unsigned short* __restrict__ out0, unsigned short* __restrict__ out1) {
  __shared__ __align__(16) unsigned short sA[2][128 * 32];
  __shared__ __align__(16) unsigned short sB[2][128 * 32];
  const int t = threadIdx.x;
  const int lane = t & 63, l15 = lane & 15, quad = lane >> 4;
  const int w = t >> 6, wm = w >> 1, wn = w & 1;
  const int m0 = blockIdx.y * 128, n0 = blockIdx.x * 128;
  const int K = 1024;

  floatx4 acc[4][4];
  const floatx4 z4 = {0.f, 0.f, 0.f, 0.f};
  #pragma unroll
  for (int i = 0; i < 4; i++)
    #pragma unroll
    for (int j = 0; j < 4; j++) acc[i][j] = z4;

  for (int kt = 0; kt < 16; ++kt) {
    const int k0 = kt << 6;
    __syncthreads();
    #pragma unroll
    for (int h = 0; h < 2; ++h) {
      #pragma unroll
      for (int c = 0; c < 2; ++c) {
        int slot = c * 256 + t;
        int row = slot >> 2, col = (slot & 3) << 3;
        async_copy16(&sA[h][slot * 8], &A[(m0 + row) * K + k0 + h * 32 + col]);
        async_copy16(&sB[h][slot * 8], &Bw[(n0 + row) * K + k0 + h * 32 + col]);
      }
    }
    __syncthreads();
    #pragma unroll
    for (int h = 0; h < 2; ++h) {
      short8 af[4], bf[4];
      #pragma unroll
      for (int mr = 0; mr < 4; mr++)
        af[mr] = *(const short8*)&sA[h][(wm * 64 + mr * 16 + l15) * 32 + quad * 8];
      #pragma unroll
      for (int nr = 0; nr < 4; nr++)
        bf[nr] = *(const short8*)&sB[h][(wn * 64 + nr * 16 + l15) * 32 + quad * 8];
      #pragma unroll
      for (int mr = 0; mr < 4; mr++)
        #pragma unroll
        for (int nr = 0; nr < 4; nr++)
          acc[mr][nr] = __builtin_amdgcn_mfma_f32_16x16x32_bf16(af[mr], bf[nr], acc[mr][nr], 0, 0, 0);
    }
  }

  #pragma unroll
  for (int mr = 0; mr < 4; mr++) {
    int gm0 = m0 + wm * 64 + mr * 16 + quad * 4;
    #pragma unroll
    for (int nr = 0; nr < 4; nr++) {
      int gn = n0 + wn * 64 + nr * 16 + l15;
      float bv = bias[gn];
      unsigned short* dst = (gn < 1024) ? (out0 + gn) : (out1 + gn - 1024);
      #pragma unroll
      for (int r = 0; r < 4; r++) {
        float v = acc[mr][nr][r] + bv;
        dst[(long)(gm0 + r) * 1024] = f2b(silu_f(v));
      }
    }
  }
}

// ---------------------------------------------------------------- GEMM out_proj
// 128x64 tile, BK=64 dual sub-buffers. 16 K-iterations.
// outf[m][n] = acc + bias[n] + src[m][n]  (f32), N=K=1024.
__global__ __launch_bounds__(256, 2) void gemm_out(
    const unsigned short* __restrict__ A, const unsigned short* __restrict__ Bw,
    const float* __restrict__ bias, const float* __restrict__ src,
    float* __restrict__ outf) {
  __shared__ __align__(16) unsigned short sA[2][128 * 32];
  __shared__ __align__(16) unsigned short sB[2][64 * 32];
  const int t = threadIdx.x;
  const int lane = t & 63, l15 = lane & 15, quad = lane >> 4;
  const int w = t >> 6;
  const int m0 = blockIdx.y * 128, n0 = blockIdx.x * 64;

  floatx4 acc[2][4];
  const floatx4 z4 = {0.f, 0.f, 0.f, 0.f};
  #pragma unroll
  for (int i = 0; i < 2; i++)
    #pragma unroll
    for (int j = 0; j < 4; j++) acc[i][j] = z4;

  for (int kt = 0; kt < 16; ++kt) {
    const int k0 = kt << 6;
    __syncthreads();
    #pragma unroll
    for (int h = 0; h < 2; ++h) {
      #pragma unroll
      for (int c = 0; c < 2; ++c) {
        int slot = c * 256 + t;
        int row = slot >> 2, col = (slot & 3) << 3;
        async_copy16(&sA[h][slot * 8], &A[(m0 + row) * 1024 + k0 + h * 32 + col]);
      }
      { int row = t >> 2, col = (t & 3) << 3;
        async_copy16(&sB[h][t * 8], &Bw[(n0 + row) * 1024 + k0 + h * 32 + col]); }
    }
    __syncthreads();
    #pragma unroll
    for (int h = 0; h < 2; ++h) {
      short8 af[2], bf[4];
      #pragma unroll
      for (int mr = 0; mr < 2; mr++)
        af[mr] = *(const short8*)&sA[h][(w * 32 + mr * 16 + l15) * 32 + quad * 8];
      #pragma unroll
      for (int nr = 0; nr < 4; nr++)
        bf[nr] = *(const short8*)&sB[h][(nr * 16 + l15) * 32 + quad * 8];
      #pragma unroll
      for (int mr = 0; mr < 2; mr++)
        #pragma unroll
        for (int nr = 0; nr < 4; nr++)
          acc[mr][nr] = __builtin_amdgcn_mfma_f32_16x16x32_bf16(af[mr], bf[nr], acc[mr][nr], 0, 0, 0);
    }
  }

  #pragma unroll
  for (int mr = 0; mr < 2; mr++) {
    int gm0 = m0 + w * 32 + mr * 16 + quad * 4;
    #pragma unroll
    for (int nr = 0; nr < 4; nr++) {
      int gn = n0 + nr * 16 + l15;
      float bv = bias[gn];
      #pragma unroll
      for (int r = 0; r < 4; r++) {
        long idx = (long)(gm0 + r) * 1024 + gn;
        outf[idx] = acc[mr][nr][r] + bv + src[idx];
      }
    }
  }
}

// ---------------------------------------------------------------- attention v5
// Occupancy play: LDS 35840 B (single sK + single sVt) + launch_bounds(256,4)
//   -> 4 blocks/CU, 16 waves/CU (was 2 blocks / 8 waves).
// grid 1024 = (pair 0..15) x (sub 0..1) x (bh 0..31); block processes q-rows
//   [qi*64+sub*32, +32) for qi in {pair, 31-pair} -> exactly 17 k-iters/block,
//   all blocks co-resident: uniform, decay-free, dispatch-order-independent.
// Per k-iter (2 barriers, single buffer): read kf+vb BEFORE 2nd barrier, then
//   QK (A=K,B=Q) -> silu/mask -> pack -> in-wave bperm transpose -> PV ->
//   write_kv(kt+1). Epilogue: 4-wave partial-O LDS reduce, gated = O*u.
#define SKS 72
#define SVS 136
__device__ __forceinline__ void write_kv(unsigned short* sKp, unsigned short* sVp,
                                         const short8* kv, int rg, int dg, int swz0) {
  #pragma unroll
  for (int i = 0; i < 4; ++i)
    *(short8*)&sKp[(rg * 4 + i) * SKS + dg * 8] = kv[i];
  intx4 k0 = __builtin_bit_cast(intx4, kv[0]);
  intx4 k1 = __builtin_bit_cast(intx4, kv[1]);
  intx4 k2 = __builtin_bit_cast(intx4, kv[2]);
  intx4 k3 = __builtin_bit_cast(intx4, kv[3]);
  #pragma unroll
  for (int jj = 0; jj < 4; ++jj) {
    unsigned lo = __builtin_amdgcn_perm((unsigned)k1[jj], (unsigned)k0[jj], 0x05040100u);
    unsigned hi = __builtin_amdgcn_perm((unsigned)k3[jj], (unsigned)k2[jj], 0x05040100u);
    int j = 2 * jj, d = dg * 8 + j;
    int gsw = (swz0 + j) & 15;
    *(unsigned long long*)&sVp[d * SVS + gsw * 8 + (rg & 1) * 4] =
        (unsigned long long)lo | ((unsigned long long)hi << 32);
    lo = __builtin_amdgcn_perm((unsigned)k1[jj], (unsigned)k0[jj], 0x07060302u);
    hi = __builtin_amdgcn_perm((unsigned)k3[jj], (unsigned)k2[jj], 0x07060302u);
    j = 2 * jj + 1; d = dg * 8 + j;
    gsw = (swz0 + j) & 15;
    *(unsigned long long*)&sVp[d * SVS + gsw * 8 + (rg & 1) * 4] =
        (unsigned long long)lo | ((unsigned long long)hi << 32);
  }
}

__global__ __launch_bounds__(256, 4) void attn_kernel(
    const unsigned short* __restrict__ qkv, const unsigned short* __restrict__ u,
    unsigned short* __restrict__ gated) {
  __shared__ __align__(16) unsigned char smem[18432 + 17408];  // 35840 B
  unsigned short* sK  = (unsigned short*)smem;                 // [128][72]
  unsigned short* sVt = (unsigned short*)(smem + 18432);       // [64][136]
  unsigned short* sQ  = sVt;                                   // [32][72] overlay
  float*          sR  = (float*)smem;                          // [2][32][68] epilogue

  const int t = threadIdx.x, lane = t & 63, l15 = lane & 15, quad = lane >> 4;
  const int w = t >> 6;
  const int pair = blockIdx.x >> 6, sub = (blockIdx.x >> 5) & 1, bh = blockIdx.x & 31;
  const int b = bh >> 4, h = bh & 15;
  const long base = (long)b * 1024 + h * 64;   // + s*2048
  const int rg = t >> 3, dg = t & 7;           // staging roles
  const int swz0 = (rg >> 1) + dg;             // sVt write swizzle base
  const int addr_lo = 4 * (l15 + 32 * (quad & 1));
  const int addr_hi = addr_lo + 64;
  const bool qhi = quad >= 2;                  // selects source m-tile
  const int vswz = w * 4 + quad + (l15 & 7) + (l15 >> 3);  // sVt read swizzle base
  const floatx4 z4 = {0.f, 0.f, 0.f, 0.f};

  for (int half = 0; half < 2; ++half) {
    const int qi = half ? (31 - pair) : pair;
    const int q0 = qi * 64 + sub * 32;
    const int nkt = (qi >> 1) + 1;

    // ---- stage Q (32 rows -> sVt overlay); prior sVt reads done at last B_B /
    //      prior sR reads protected by Bq below ----
    {
      int row = t >> 3, cg = t & 7;
      *(short8*)&sQ[row * SKS + cg * 8] =
          *(const short8*)&qkv[base + (long)(q0 + row) * 2048 + cg * 8];
    }
    __syncthreads();                         // Bq: sQ visible; prior-epilogue reads done
    short8 qf[2][2];
    #pragma unroll
    for (int nt = 0; nt < 2; nt++)
      #pragma unroll
      for (int ks = 0; ks < 2; ks++)
        qf[nt][ks] = *(const short8*)&sQ[(nt * 16 + l15) * SKS + ks * 32 + quad * 8];
    __syncthreads();                         // Bq2: qf reads done -> sVt writable
    // ---- stage K-tile 0 ----
    short8 kv[4];
    #pragma unroll
    for (int i = 0; i < 4; ++i)
      kv[i] = *(const short8*)&qkv[base + (long)(rg * 4 + i) * 2048 + dg * 8];
    write_kv(sK, sVt, kv, rg, dg, swz0);

    floatx4 oacc[2][4];
    #pragma unroll
    for (int i = 0; i < 2; i++)
      #pragma unroll
      for (int j = 0; j < 4; j++) oacc[i][j] = z4;

    for (int kt = 0; kt < nkt; ++kt) {
      __syncthreads();                       // B_A: staging of tile kt visible
      // ---- read all LDS operands for tile kt ----
      short8 kf[2][2];
      #pragma unroll
      for (int mt = 0; mt < 2; mt++)
        #pragma unroll
        for (int ks = 0; ks < 2; ks++)
          kf[mt][ks] = *(const short8*)&sK[(w * 32 + mt * 16 + l15) * SKS + ks * 32 + quad * 8];
      short8 vb[4];
      #pragma unroll
      for (int dt = 0; dt < 4; dt++)
        vb[dt] = *(const short8*)&sVt[(dt * 16 + l15) * SVS + ((vswz + 2 * dt) & 15) * 8];
      // ---- prefetch global K-tile kt+1 ----
      const bool more = (kt + 1 < nkt);
      if (more) {
        const long nb = base + (long)((kt + 1) * 128) * 2048;
        #pragma unroll
        for (int i = 0; i < 4; ++i)
          kv[i] = *(const short8*)&qkv[nb + (long)(rg * 4 + i) * 2048 + dg * 8];
      }
      __syncthreads();                       // B_B: all reads done -> buffers writable
      // ---- S^T = K Q^T : wave owns t-rows [w*32, +32), q = q0..q0+32 ----
      floatx4 sacc[2][2];
      #pragma unroll
      for (int i = 0; i < 2; i++) { sacc[i][0] = z4; sacc[i][1] = z4; }
      #pragma unroll
      for (int ks = 0; ks < 2; ++ks)
        #pragma unroll
        for (int mt = 0; mt < 2; mt++)
          #pragma unroll
          for (int nt = 0; nt < 2; nt++)
            sacc[mt][nt] = __builtin_amdgcn_mfma_f32_16x16x32_bf16(
                kf[mt][ks], qf[nt][ks], sacc[mt][nt], 0, 0, 0);
      // ---- scale, silu, mask (diag only); pack bf16 pairs ----
      const bool diag = (kt == nkt - 1);
      const int tw = kt * 128 + w * 32;
      unsigned p0[2][2], p1[2][2];
      #pragma unroll
      for (int mt = 0; mt < 2; mt++)
        #pragma unroll
        for (int nt = 0; nt < 2; nt++) {
          float v[4];
          if (diag) {
            int qq = q0 + nt * 16 + l15;
            #pragma unroll
            for (int r = 0; r < 4; r++) {
              int tt = tw + mt * 16 + quad * 4 + r;
              float x = silu_f(sacc[mt][nt][r] * 0.125f);
              v[r] = (qq < tt) ? 0.f : x;
            }
          } else {
            #pragma unroll
            for (int r = 0; r < 4; r++) v[r] = silu_f(sacc[mt][nt][r] * 0.125f);
          }
          p0[mt][nt] = __builtin_amdgcn_perm(__builtin_bit_cast(unsigned, v[1]),
                                             __builtin_bit_cast(unsigned, v[0]), 0x07060302u);
          p1[mt][nt] = __builtin_amdgcn_perm(__builtin_bit_cast(unsigned, v[3]),
                                             __builtin_bit_cast(unsigned, v[2]), 0x07060302u);
        }
      // ---- PV: O_partial[q][d] += P[q][t-slice] * V[t-slice][d] ----
      #pragma unroll
      for (int qt = 0; qt < 2; qt++) {
        intx4 pa;
        #pragma unroll
        for (int jj = 0; jj < 4; jj++) {
          int addr = (jj >> 1) ? addr_hi : addr_lo;
          int lo, hi;
          if (jj & 1) {
            lo = __builtin_amdgcn_ds_bpermute(addr, (int)p1[0][qt]);
            hi = __builtin_amdgcn_ds_bpermute(addr, (int)p1[1][qt]);
          } else {
            lo = __builtin_amdgcn_ds_bpermute(addr, (int)p0[0][qt]);
            hi = __builtin_amdgcn_ds_bpermute(addr, (int)p0[1][qt]);
          }
          pa[jj] = qhi ? hi : lo;
        }
        short8 paf = __builtin_bit_cast(short8, pa);
        #pragma unroll
        for (int dt = 0; dt < 4; dt++)
          oacc[qt][dt] = __builtin_amdgcn_mfma_f32_16x16x32_bf16(paf, vb[dt], oacc[qt][dt], 0, 0, 0);
      }
      // ---- stage tile kt+1 into the (now writable) single buffers ----
      if (more) write_kv(sK, sVt, kv, rg, dg, swz0);
    }

    // ---- epilogue: 4-wave partial-O reduce in sR (overlaps sK), gated = O*u ----
    // After final B_B no thread reads sK/sVt, so sR writes are safe.
    float* plane = sR + (w & 1) * 2176;      // [32][68] f32
    if (w < 2) {
      #pragma unroll
      for (int qt = 0; qt < 2; qt++)
        #pragma unroll
        for (int dt = 0; dt < 4; dt++)
          #pragma unroll
          for (int r = 0; r < 4; r++)
            plane[(qt * 16 + quad * 4 + r) * 68 + dt * 16 + l15] = oacc[qt][dt][r];
    }
    __syncthreads();                         // E2
    if (w >= 2) {
      #pragma unroll
      for (int qt = 0; qt < 2; qt++)
        #pragma unroll
        for (int dt = 0; dt < 4; dt++)
          #pragma unroll
          for (int r = 0; r < 4; r++)
            plane[(qt * 16 + quad * 4 + r) * 68 + dt * 16 + l15] += oacc[qt][dt][r];
    }
    __syncthreads();                         // E3
    {
      const int erow = t >> 3, edg = t & 7;  // row 0..31, 8-d group 0..7
      const long grow = (long)(q0 + erow) * 2048 + base + edg * 8;
      short8 u0 = *(const short8*)&u[grow];
      const float* r0p = sR + erow * 68 + edg * 8;
      const float* r1p = r0p + 2176;
      short8 g0;
      #pragma unroll
      for (int j = 0; j < 8; ++j)
        g0[j] = (short)f2b((r0p[j] + r1p[j]) * b2f((unsigned short)u0[j]));
      *(short8*)&gated[grow] = g0;
    }
    // half=1 restages sQ into sVt: prior sR reads are ordered by Bq.
  }
}

// ---------------------------------------------------------------- launch
extern "C" void kernel_launch(void* const* d_in, const int* in_sizes, int n_in,
                              void* d_out, int out_size, void* d_ws, size_t ws_size,
                              hipStream_t stream) {
  const float* src = (const float*)d_in[0];
  // d_in[1] = src_mask: tril, causality handled structurally
  const float* w1  = (const float*)d_in[2];
  const float* b1  = (const float*)d_in[3];
  const float* w2  = (const float*)d_in[4];
  const float* b2  = (const float*)d_in[5];
  const float* lng = (const float*)d_in[6];
  const float* lnb = (const float*)d_in[7];
  float* out = (float*)d_out;

  char* ws = (char*)d_ws;
  unsigned short* xn    = (unsigned short*)(ws + 0);          // 4096x1024 bf16
  unsigned short* qkv   = (unsigned short*)(ws + 8388608);    // 4096x1024 bf16
  unsigned short* uu    = (unsigned short*)(ws + 16777216);   // 4096x1024 bf16
  unsigned short* gated = (unsigned short*)(ws + 25165824);   // 4096x1024 bf16
  unsigned short* w1b   = (unsigned short*)(ws + 33554432);   // 2048x1024 bf16
  unsigned short* w2b   = (unsigned short*)(ws + 37748736);   // 1024x1024 bf16

  prep_kernel<<<4096, 256, 0, stream>>>(w1, w1b, w2, w2b, src, lng, lnb, xn);
  gemm_in<<<dim3(16, 32), 256, 0, stream>>>(xn, w1b, b1, qkv, uu);
  attn_kernel<<<1024, 256, 0, stream>>>(qkv, uu, gated);
  gemm_out<<<dim3(16, 32), 256, 0, stream>>>(gated, w2b, b2, src, out);
}

// Round 10
// 192.871 us; speedup vs baseline: 1.0317x; 1.0317x over previous
//
#include <hip/hip_runtime.h>

// ---------------------------------------------------------------------------
// HSTU encoder layer, MI355X.  S=2048 B=2 E=1024 H=16 D=64, M = S*B = 4096.
// prep(cvt W + LN) -> GEMM dbuf BK=64 (in_proj,silu) -> attn (S^T QK, silu-mask,
//   bpermute transpose, partial-O PV, LDS reduce, *u) -> GEMM dbuf (out_proj,+src)
// All matmuls: v_mfma_f32_16x16x32_bf16, f32 accum.
// GEMM K-loop: double-buffered LDS, ONE barrier/iter, loads for kt+1 issued
// before computing kt so MFMA covers the global->LDS latency (at 2 blocks/CU
// there is little inter-block TLP to hide it implicitly).
// ---------------------------------------------------------------------------

typedef __attribute__((ext_vector_type(8))) short  short8;   // 8 bf16 = 4 VGPR
typedef __attribute__((ext_vector_type(4))) float  floatx4;  // MFMA C/D frag
typedef __attribute__((ext_vector_type(4))) float  fvec4;
typedef __attribute__((ext_vector_type(4))) unsigned short usvec4;
typedef __attribute__((ext_vector_type(4))) int    intx4;

__device__ __forceinline__ unsigned short f2b(float f) {  // f32 -> bf16 RNE
  unsigned u = __builtin_bit_cast(unsigned, f);
  u += 0x7FFFu + ((u >> 16) & 1u);
  return (unsigned short)(u >> 16);
}
__device__ __forceinline__ float b2f(unsigned short h) {
  unsigned u = ((unsigned)h) << 16;
  return __builtin_bit_cast(float, u);
}
// silu via raw v_exp/v_rcp: x<<0 -> exp2(+inf)->rcp->0 OK; x>>0 -> 1*x OK.
__device__ __forceinline__ float silu_f(float x) {
  float e = __builtin_amdgcn_exp2f(-1.44269504f * x);
  return x * __builtin_amdgcn_rcpf(1.f + e);
}
__device__ __forceinline__ void async_copy16(void* lds, const void* g) {
  __builtin_amdgcn_global_load_lds(
      (__attribute__((address_space(1))) void*)(g),
      (__attribute__((address_space(3))) void*)(lds), 16, 0, 0);
}

// ---------------------------------------------------------------- prep:
// blocks [0,3072): cvt w1/w2 f32->bf16.  blocks [3072,4096): LayerNorm
// (one wave per row, shfl_xor reduce).
__global__ __launch_bounds__(256) void prep_kernel(
    const float* __restrict__ w1, unsigned short* __restrict__ w1b,
    const float* __restrict__ w2, unsigned short* __restrict__ w2b,
    const float* __restrict__ x, const float* __restrict__ g,
    const float* __restrict__ b, unsigned short* __restrict__ xn) {
  const int blk = blockIdx.x;
  if (blk < 3072) {
    int i = blk * 256 + threadIdx.x;      // over 786432 fvec4 groups
    const float* s; unsigned short* d; int j;
    if (i < 524288) { s = w1; d = w1b; j = i; } else { s = w2; d = w2b; j = i - 524288; }
    fvec4 v = ((const fvec4*)s)[j];
    usvec4 o = { f2b(v.x), f2b(v.y), f2b(v.z), f2b(v.w) };
    ((usvec4*)d)[j] = o;
    return;
  }
  const int lane = threadIdx.x & 63;
  const int row = (blk - 3072) * 4 + (threadIdx.x >> 6);
  const fvec4* xr = (const fvec4*)(x + (long)row * 1024);
  fvec4 v[4];
  float s = 0.f, s2 = 0.f;
  #pragma unroll
  for (int c = 0; c < 4; ++c) {
    v[c] = xr[lane + 64 * c];
    s  += v[c].x + v[c].y + v[c].z + v[c].w;
    s2 += v[c].x*v[c].x + v[c].y*v[c].y + v[c].z*v[c].z + v[c].w*v[c].w;
  }
  #pragma unroll
  for (int off = 32; off; off >>= 1) { s += __shfl_xor(s, off); s2 += __shfl_xor(s2, off); }
  float mu  = s * (1.f / 1024.f);
  float var = s2 * (1.f / 1024.f) - mu * mu;
  float rs  = rsqrtf(var + 1e-5f);
  usvec4* outr = (usvec4*)(xn + (long)row * 1024);
  #pragma unroll
  for (int c = 0; c < 4; ++c) {
    fvec4 gg = ((const fvec4*)g)[lane + 64 * c];
    fvec4 bb = ((const fvec4*)b)[lane + 64 * c];
    usvec4 o = { f2b((v[c].x - mu) * rs * gg.x + bb.x),
                 f2b((v[c].y - mu) * rs * gg.y + bb.y),
                 f2b((v[c].z - mu) * rs * gg.z + bb.z),
                 f2b((v[c].w - mu) * rs * gg.w + bb.w) };
    outr[lane + 64 * c] = o;
  }
}

// ---------------------------------------------------------------- GEMM in_proj
// C = A * Bw^T, 128x128 tile, BK=64 (dual 32-wide sub-buffers), double-buffered
// LDS, one barrier per K-iter; prefetch loads issued before the compute phase.
// epilogue: v=silu(v+bias); n<1024 -> qkv else u (both [m][1024] bf16)
__global__ __launch_bounds__(256, 2) void gemm_in(
    const unsigned short* __restrict__ A, const unsigned short* __restrict__ Bw,
    const float* __restrict__ bias,
    unsigned short* __restrict__ out0, unsigned short* __restrict__ out1) {
  __shared__ __align__(16) unsigned short sA[2][2][128 * 32];   // 32 KB
  __shared__ __align__(16) unsigned short sB[2][2][128 * 32];   // 32 KB
  const int t = threadIdx.x;
  const int lane = t & 63, l15 = lane & 15, quad = lane >> 4;
  const int w = t >> 6, wm = w >> 1, wn = w & 1;
  const int m0 = blockIdx.y * 128, n0 = blockIdx.x * 128;
  const int K = 1024;

  floatx4 acc[4][4];
  const floatx4 z4 = {0.f, 0.f, 0.f, 0.f};
  #pragma unroll
  for (int i = 0; i < 4; i++)
    #pragma unroll
    for (int j = 0; j < 4; j++) acc[i][j] = z4;

  // prologue: stage kt=0 into buffer 0
  #pragma unroll
  for (int h = 0; h < 2; ++h)
    #pragma unroll
    for (int c = 0; c < 2; ++c) {
      int slot = c * 256 + t, row = slot >> 2, col = (slot & 3) << 3;
      async_copy16(&sA[0][h][slot * 8], &A[(m0 + row) * K + h * 32 + col]);
      async_copy16(&sB[0][h][slot * 8], &Bw[(n0 + row) * K + h * 32 + col]);
    }

  for (int kt = 0; kt < 16; ++kt) {
    const int buf = kt & 1;
    __syncthreads();   // staging of kt visible; reads of kt-1 (buf^1) done
    if (kt + 1 < 16) {
      const int k0 = (kt + 1) << 6;
      #pragma unroll
      for (int h = 0; h < 2; ++h)
        #pragma unroll
        for (int c = 0; c < 2; ++c) {
          int slot = c * 256 + t, row = slot >> 2, col = (slot & 3) << 3;
          async_copy16(&sA[buf ^ 1][h][slot * 8], &A[(m0 + row) * K + k0 + h * 32 + col]);
          async_copy16(&sB[buf ^ 1][h][slot * 8], &Bw[(n0 + row) * K + k0 + h * 32 + col]);
        }
    }
    #pragma unroll
    for (int h = 0; h < 2; ++h) {
      short8 af[4], bf[4];
      #pragma unroll
      for (int mr = 0; mr < 4; mr++)
        af[mr] = *(const short8*)&sA[buf][h][(wm * 64 + mr * 16 + l15) * 32 + quad * 8];
      #pragma unroll
      for (int nr = 0; nr < 4; nr++)
        bf[nr] = *(const short8*)&sB[buf][h][(wn * 64 + nr * 16 + l15) * 32 + quad * 8];
      #pragma unroll
      for (int mr = 0; mr < 4; mr++)
        #pragma unroll
        for (int nr = 0; nr < 4; nr++)
          acc[mr][nr] = __builtin_amdgcn_mfma_f32_16x16x32_bf16(af[mr], bf[nr], acc[mr][nr], 0, 0, 0);
    }
  }

  #pragma unroll
  for (int mr = 0; mr < 4; mr++) {
    int gm0 = m0 + wm * 64 + mr * 16 + quad * 4;
    #pragma unroll
    for (int nr = 0; nr < 4; nr++) {
      int gn = n0 + wn * 64 + nr * 16 + l15;
      float bv = bias[gn];
      unsigned short* dst = (gn < 1024) ? (out0 + gn) : (out1 + gn - 1024);
      #pragma unroll
      for (int r = 0; r < 4; r++) {
        float v = acc[mr][nr][r] + bv;
        dst[(long)(gm0 + r) * 1024] = f2b(silu_f(v));
      }
    }
  }
}

// ---------------------------------------------------------------- GEMM out_proj
// 128x64 tile, BK=64, double-buffered LDS, one barrier/iter.
// outf[m][n] = acc + bias[n] + src[m][n]  (f32), N=K=1024.
__global__ __launch_bounds__(256, 2) void gemm_out(
    const unsigned short* __restrict__ A, const unsigned short* __restrict__ Bw,
    const float* __restrict__ bias, const float* __restrict__ src,
    float* __restrict__ outf) {
  __shared__ __align__(16) unsigned short sA[2][2][128 * 32];   // 32 KB
  __shared__ __align__(16) unsigned short sB[2][2][64 * 32];    // 16 KB
  const int t = threadIdx.x;
  const int lane = t & 63, l15 = lane & 15, quad = lane >> 4;
  const int w = t >> 6;
  const int m0 = blockIdx.y * 128, n0 = blockIdx.x * 64;

  floatx4 acc[2][4];
  const floatx4 z4 = {0.f, 0.f, 0.f, 0.f};
  #pragma unroll
  for (int i = 0; i < 2; i++)
    #pragma unroll
    for (int j = 0; j < 4; j++) acc[i][j] = z4;

  // prologue: stage kt=0 into buffer 0
  #pragma unroll
  for (int h = 0; h < 2; ++h) {
    #pragma unroll
    for (int c = 0; c < 2; ++c) {
      int slot = c * 256 + t, row = slot >> 2, col = (slot & 3) << 3;
      async_copy16(&sA[0][h][slot * 8], &A[(m0 + row) * 1024 + h * 32 + col]);
    }
    { int row = t >> 2, col = (t & 3) << 3;
      async_copy16(&sB[0][h][t * 8], &Bw[(n0 + row) * 1024 + h * 32 + col]); }
  }

  for (int kt = 0; kt < 16; ++kt) {
    const int buf = kt & 1;
    __syncthreads();
    if (kt + 1 < 16) {
      const int k0 = (kt + 1) << 6;
      #pragma unroll
      for (int h = 0; h < 2; ++h) {
        #pragma unroll
        for (int c = 0; c < 2; ++c) {
          int slot = c * 256 + t, row = slot >> 2, col = (slot & 3) << 3;
          async_copy16(&sA[buf ^ 1][h][slot * 8], &A[(m0 + row) * 1024 + k0 + h * 32 + col]);
        }
        { int row = t >> 2, col = (t & 3) << 3;
          async_copy16(&sB[buf ^ 1][h][t * 8], &Bw[(n0 + row) * 1024 + k0 + h * 32 + col]); }
      }
    }
    #pragma unroll
    for (int h = 0; h < 2; ++h) {
      short8 af[2], bf[4];
      #pragma unroll
      for (int mr = 0; mr < 2; mr++)
        af[mr] = *(const short8*)&sA[buf][h][(w * 32 + mr * 16 + l15) * 32 + quad * 8];
      #pragma unroll
      for (int nr = 0; nr < 4; nr++)
        bf[nr] = *(const short8*)&sB[buf][h][(nr * 16 + l15) * 32 + quad * 8];
      #pragma unroll
      for (int mr = 0; mr < 2; mr++)
        #pragma unroll
        for (int nr = 0; nr < 4; nr++)
          acc[mr][nr] = __builtin_amdgcn_mfma_f32_16x16x32_bf16(af[mr], bf[nr], acc[mr][nr], 0, 0, 0);
    }
  }

  #pragma unroll
  for (int mr = 0; mr < 2; mr++) {
    int gm0 = m0 + w * 32 + mr * 16 + quad * 4;
    #pragma unroll
    for (int nr = 0; nr < 4; nr++) {
      int gn = n0 + nr * 16 + l15;
      float bv = bias[gn];
      #pragma unroll
      for (int r = 0; r < 4; r++) {
        long idx = (long)(gm0 + r) * 1024 + gn;
        outf[idx] = acc[mr][nr][r] + bv + src[idx];
      }
    }
  }
}

// ---------------------------------------------------------------- attention v3 (r7 revert — best measured 52.0 us)
// grid 512: block = (pair, bh), q-tiles {pair, 31-pair} -> 17 k-iters uniform.
// Per k-iter (2 barriers): wave w computes S^T[t-slice w*32..+32][all 64 q]
// (MFMA: A=K-frag, B=Q-frag); silu+mask in regs; P A-frags for PV gathered
// IN-WAVE via ds_bpermute; partial O per wave over its t-slice; epilogue:
// cross-wave LDS reduce + *u coalesced store.
#define SKS 72
#define SVS 136
__device__ __forceinline__ void write_kv(unsigned short* sKp, unsigned short* sVp,
                                         const short8* kv, int rg, int dg, int swz0) {
  #pragma unroll
  for (int i = 0; i < 4; ++i)
    *(short8*)&sKp[(rg * 4 + i) * SKS + dg * 8] = kv[i];
  intx4 k0 = __builtin_bit_cast(intx4, kv[0]);
  intx4 k1 = __builtin_bit_cast(intx4, kv[1]);
  intx4 k2 = __builtin_bit_cast(intx4, kv[2]);
  intx4 k3 = __builtin_bit_cast(intx4, kv[3]);
  #pragma unroll
  for (int jj = 0; jj < 4; ++jj) {
    unsigned lo = __builtin_amdgcn_perm((unsigned)k1[jj], (unsigned)k0[jj], 0x05040100u);
    unsigned hi = __builtin_amdgcn_perm((unsigned)k3[jj], (unsigned)k2[jj], 0x05040100u);
    int j = 2 * jj, d = dg * 8 + j;
    int gsw = (swz0 + j) & 15;
    *(unsigned long long*)&sVp[d * SVS + gsw * 8 + (rg & 1) * 4] =
        (unsigned long long)lo | ((unsigned long long)hi << 32);
    lo = __builtin_amdgcn_perm((unsigned)k1[jj], (unsigned)k0[jj], 0x07060302u);
    hi = __builtin_amdgcn_perm((unsigned)k3[jj], (unsigned)k2[jj], 0x07060302u);
    j = 2 * jj + 1; d = dg * 8 + j;
    gsw = (swz0 + j) & 15;
    *(unsigned long long*)&sVp[d * SVS + gsw * 8 + (rg & 1) * 4] =
        (unsigned long long)lo | ((unsigned long long)hi << 32);
  }
}

__global__ __launch_bounds__(256, 2) void attn_kernel(
    const unsigned short* __restrict__ qkv, const unsigned short* __restrict__ u,
    unsigned short* __restrict__ gated) {
  __shared__ __align__(16) unsigned char smem[18432 + 2 * 17408];  // 53248 B
  unsigned short* sK   = (unsigned short*)smem;                    // [128][72]
  unsigned short* sVt0 = (unsigned short*)(smem + 18432);          // [64][136]
  unsigned short* sVt1 = (unsigned short*)(smem + 18432 + 17408);  // [64][136]
  unsigned short* sQ   = sVt1;                                     // [64][72] overlay
  float*          sR   = (float*)smem;                             // [2][64][68] epilogue

  const int t = threadIdx.x, lane = t & 63, l15 = lane & 15, quad = lane >> 4;
  const int w = t >> 6;
  const int pair = blockIdx.x >> 5, bh = blockIdx.x & 31;
  const int b = bh >> 4, h = bh & 15;
  const long base = (long)b * 1024 + h * 64;   // + s*2048
  const int rg = t >> 3, dg = t & 7;           // staging roles
  const int swz0 = (rg >> 1) + dg;             // sVt write swizzle base
  const int addr_lo = 4 * (l15 + 32 * (quad & 1));
  const int addr_hi = addr_lo + 64;
  const bool qhi = quad >= 2;                  // selects source m-tile
  const int vswz = w * 4 + quad + (l15 & 7) + (l15 >> 3);  // sVt read swizzle base
  const floatx4 z4 = {0.f, 0.f, 0.f, 0.f};

  for (int half = 0; half < 2; ++half) {
    const int qi = half ? (31 - pair) : pair;
    const int q0 = qi * 64;
    const int nkt = (qi >> 1) + 1;

    if (half) __syncthreads();               // prior epilogue reads done
    // ---- stage Q (into sVt1 overlay), pull B-frags ----
    #pragma unroll
    for (int c = 0; c < 2; ++c) {
      int slot = c * 256 + t, row = slot >> 3, cg = slot & 7;
      *(short8*)&sQ[row * SKS + cg * 8] =
          *(const short8*)&qkv[base + (long)(q0 + row) * 2048 + cg * 8];
    }
    __syncthreads();
    short8 qf[4][2];
    #pragma unroll
    for (int nt = 0; nt < 4; nt++)
      #pragma unroll
      for (int ks = 0; ks < 2; ks++)
        qf[nt][ks] = *(const short8*)&sQ[(nt * 16 + l15) * SKS + ks * 32 + quad * 8];
    // ---- prologue: stage K-tile 0 (sK + sVt0; disjoint from sQ) ----
    short8 kv[4];
    #pragma unroll
    for (int i = 0; i < 4; ++i)
      kv[i] = *(const short8*)&qkv[base + (long)(rg * 4 + i) * 2048 + dg * 8];
    write_kv(sK, sVt0, kv, rg, dg, swz0);

    floatx4 oacc[4][4];
    #pragma unroll
    for (int i = 0; i < 4; i++)
      #pragma unroll
      for (int j = 0; j < 4; j++) oacc[i][j] = z4;

    for (int kt = 0; kt < nkt; ++kt) {
      unsigned short* sVtC = (kt & 1) ? sVt1 : sVt0;
      unsigned short* sVtN = (kt & 1) ? sVt0 : sVt1;
      __syncthreads();                       // T1: staging of tile kt visible
      const bool more = (kt + 1 < nkt);
      if (more) {
        const long nb = base + (long)((kt + 1) * 128) * 2048;
        #pragma unroll
        for (int i = 0; i < 4; ++i)
          kv[i] = *(const short8*)&qkv[nb + (long)(rg * 4 + i) * 2048 + dg * 8];
      }
      short8 kf[2][2];
      #pragma unroll
      for (int mt = 0; mt < 2; mt++)
        #pragma unroll
        for (int ks = 0; ks < 2; ks++)
          kf[mt][ks] = *(const short8*)&sK[(w * 32 + mt * 16 + l15) * SKS + ks * 32 + quad * 8];
      __syncthreads();                       // T2: all kf reads done -> sK writable
      // ---- S^T = K Q^T : wave owns t-rows [w*32, w*32+32) ----
      floatx4 sacc[2][4];
      #pragma unroll
      for (int i = 0; i < 2; i++)
        #pragma unroll
        for (int j = 0; j < 4; j++) sacc[i][j] = z4;
      #pragma unroll
      for (int ks = 0; ks < 2; ++ks)
        #pragma unroll
        for (int mt = 0; mt < 2; mt++)
          #pragma unroll
          for (int nt = 0; nt < 4; nt++)
            sacc[mt][nt] = __builtin_amdgcn_mfma_f32_16x16x32_bf16(
                kf[mt][ks], qf[nt][ks], sacc[mt][nt], 0, 0, 0);
      // ---- scale, silu, mask (diag only); pack bf16 pairs ----
      const bool diag = (kt == nkt - 1);
      const int tw = kt * 128 + w * 32;
      unsigned p0[2][4], p1[2][4];
      #pragma unroll
      for (int mt = 0; mt < 2; mt++)
        #pragma unroll
        for (int nt = 0; nt < 4; nt++) {
          float v[4];
          if (diag) {
            int qq = q0 + nt * 16 + l15;
            #pragma unroll
            for (int r = 0; r < 4; r++) {
              int tt = tw + mt * 16 + quad * 4 + r;
              float x = silu_f(sacc[mt][nt][r] * 0.125f);
              v[r] = (qq < tt) ? 0.f : x;
            }
          } else {
            #pragma unroll
            for (int r = 0; r < 4; r++) v[r] = silu_f(sacc[mt][nt][r] * 0.125f);
          }
          p0[mt][nt] = __builtin_amdgcn_perm(__builtin_bit_cast(unsigned, v[1]),
                                             __builtin_bit_cast(unsigned, v[0]), 0x07060302u);
          p1[mt][nt] = __builtin_amdgcn_perm(__builtin_bit_cast(unsigned, v[3]),
                                             __builtin_bit_cast(unsigned, v[2]), 0x07060302u);
        }
      // ---- PV: O_partial[q][d] += P[q][t-slice] * V[t-slice][d] ----
      short8 vb[4];
      #pragma unroll
      for (int dt = 0; dt < 4; dt++)
        vb[dt] = *(const short8*)&sVtC[(dt * 16 + l15) * SVS + ((vswz + 2 * dt) & 15) * 8];
      #pragma unroll
      for (int qt = 0; qt < 4; qt++) {
        intx4 pa;
        #pragma unroll
        for (int jj = 0; jj < 4; jj++) {
          int addr = (jj >> 1) ? addr_hi : addr_lo;
          int lo, hi;
          if (jj & 1) {
            lo = __builtin_amdgcn_ds_bpermute(addr, (int)p1[0][qt]);
            hi = __builtin_amdgcn_ds_bpermute(addr, (int)p1[1][qt]);
          } else {
            lo = __builtin_amdgcn_ds_bpermute(addr, (int)p0[0][qt]);
            hi = __builtin_amdgcn_ds_bpermute(addr, (int)p0[1][qt]);
          }
          pa[jj] = qhi ? hi : lo;
        }
        short8 paf = __builtin_bit_cast(short8, pa);
        #pragma unroll
        for (int dt = 0; dt < 4; dt++)
          oacc[qt][dt] = __builtin_amdgcn_mfma_f32_16x16x32_bf16(paf, vb[dt], oacc[qt][dt], 0, 0, 0);
      }
      // ---- stage tile kt+1 (writes overlap nothing being read) ----
      if (more) write_kv(sK, sVtN, kv, rg, dg, swz0);
    }

    // ---- epilogue: cross-wave partial-O reduce, gated = O*u ----
    __syncthreads();                         // E1: all k-loop LDS reads done
    float* plane = sR + (w & 1) * 4352;      // [64][68]
    if (w < 2) {
      #pragma unroll
      for (int qt = 0; qt < 4; qt++)
        #pragma unroll
        for (int dt = 0; dt < 4; dt++)
          #pragma unroll
          for (int r = 0; r < 4; r++)
            plane[(qt * 16 + quad * 4 + r) * 68 + dt * 16 + l15] = oacc[qt][dt][r];
    }
    __syncthreads();                         // E2
    if (w >= 2) {
      #pragma unroll
      for (int qt = 0; qt < 4; qt++)
        #pragma unroll
        for (int dt = 0; dt < 4; dt++)
          #pragma unroll
          for (int r = 0; r < 4; r++)
            plane[(qt * 16 + quad * 4 + r) * 68 + dt * 16 + l15] += oacc[qt][dt][r];
    }
    __syncthreads();                         // E3
    {
      const int erow = t >> 2, edg = t & 3;
      const long grow = (long)(q0 + erow) * 2048 + base + edg * 16;
      short8 u0 = *(const short8*)&u[grow];
      short8 u1 = *(const short8*)&u[grow + 8];
      const float* r0p = sR + erow * 68 + edg * 16;
      const float* r1p = r0p + 4352;
      float o[16];
      #pragma unroll
      for (int c = 0; c < 4; c++) {
        fvec4 a = ((const fvec4*)r0p)[c];
        fvec4 bsum = ((const fvec4*)r1p)[c];
        o[4*c+0] = a.x + bsum.x; o[4*c+1] = a.y + bsum.y;
        o[4*c+2] = a.z + bsum.z; o[4*c+3] = a.w + bsum.w;
      }
      short8 g0, g1;
      #pragma unroll
      for (int j = 0; j < 8; ++j) {
        g0[j] = (short)f2b(o[j]     * b2f((unsigned short)u0[j]));
        g1[j] = (short)f2b(o[j + 8] * b2f((unsigned short)u1[j]));
      }
      *(short8*)&gated[grow]     = g0;
      *(short8*)&gated[grow + 8] = g1;
    }
  }
}

// ---------------------------------------------------------------- launch
extern "C" void kernel_launch(void* const* d_in, const int* in_sizes, int n_in,
                              void* d_out, int out_size, void* d_ws, size_t ws_size,
                              hipStream_t stream) {
  const float* src = (const float*)d_in[0];
  // d_in[1] = src_mask: tril, causality handled structurally
  const float* w1  = (const float*)d_in[2];
  const float* b1  = (const float*)d_in[3];
  const float* w2  = (const float*)d_in[4];
  const float* b2  = (const float*)d_in[5];
  const float* lng = (const float*)d_in[6];
  const float* lnb = (const float*)d_in[7];
  float* out = (float*)d_out;

  char* ws = (char*)d_ws;
  unsigned short* xn    = (unsigned short*)(ws + 0);          // 4096x1024 bf16
  unsigned short* qkv   = (unsigned short*)(ws + 8388608);    // 4096x1024 bf16
  unsigned short* uu    = (unsigned short*)(ws + 16777216);   // 4096x1024 bf16
  unsigned short* gated = (unsigned short*)(ws + 25165824);   // 4096x1024 bf16
  unsigned short* w1b   = (unsigned short*)(ws + 33554432);   // 2048x1024 bf16
  unsigned short* w2b   = (unsigned short*)(ws + 37748736);   // 1024x1024 bf16

  prep_kernel<<<4096, 256, 0, stream>>>(w1, w1b, w2, w2b, src, lng, lnb, xn);
  gemm_in<<<dim3(16, 32), 256, 0, stream>>>(xn, w1b, b1, qkv, uu);
  attn_kernel<<<512, 256, 0, stream>>>(qkv, uu, gated);
  gemm_out<<<dim3(16, 32), 256, 0, stream>>>(gated, w2b, b2, src, out);
}

// Round 11
// 185.688 us; speedup vs baseline: 1.0716x; 1.0387x over previous
//
#include <hip/hip_runtime.h>

// ---------------------------------------------------------------------------
// HSTU encoder layer, MI355X.  S=2048 B=2 E=1024 H=16 D=64, M = S*B = 4096.
// prep(cvt W + LN) -> GEMM BK=64 (in_proj,silu) -> attn (S^T QK, silu-mask,
//   bpermute transpose, partial-O PV, even-qi diag-half skip, LDS reduce, *u)
//   -> GEMM BK=64 128x64 (out_proj,+src)
// All matmuls: v_mfma_f32_16x16x32_bf16, f32 accum.
// GEMM note: single-buffer BK=64 (r7) is the best measured; explicit LDS
// double-buffering regressed (r10: +5.8 us) — matches m99/m100 guidance.
// ---------------------------------------------------------------------------

typedef __attribute__((ext_vector_type(8))) short  short8;   // 8 bf16 = 4 VGPR
typedef __attribute__((ext_vector_type(4))) float  floatx4;  // MFMA C/D frag
typedef __attribute__((ext_vector_type(4))) float  fvec4;
typedef __attribute__((ext_vector_type(4))) unsigned short usvec4;
typedef __attribute__((ext_vector_type(4))) int    intx4;

__device__ __forceinline__ unsigned short f2b(float f) {  // f32 -> bf16 RNE
  unsigned u = __builtin_bit_cast(unsigned, f);
  u += 0x7FFFu + ((u >> 16) & 1u);
  return (unsigned short)(u >> 16);
}
__device__ __forceinline__ float b2f(unsigned short h) {
  unsigned u = ((unsigned)h) << 16;
  return __builtin_bit_cast(float, u);
}
// silu via raw v_exp/v_rcp: x<<0 -> exp2(+inf)->rcp->0 OK; x>>0 -> 1*x OK.
__device__ __forceinline__ float silu_f(float x) {
  float e = __builtin_amdgcn_exp2f(-1.44269504f * x);
  return x * __builtin_amdgcn_rcpf(1.f + e);
}
__device__ __forceinline__ void async_copy16(void* lds, const void* g) {
  __builtin_amdgcn_global_load_lds(
      (__attribute__((address_space(1))) void*)(g),
      (__attribute__((address_space(3))) void*)(lds), 16, 0, 0);
}

// ---------------------------------------------------------------- prep:
// blocks [0,3072): cvt w1/w2 f32->bf16.  blocks [3072,4096): LayerNorm
// (one wave per row, shfl_xor reduce).
__global__ __launch_bounds__(256) void prep_kernel(
    const float* __restrict__ w1, unsigned short* __restrict__ w1b,
    const float* __restrict__ w2, unsigned short* __restrict__ w2b,
    const float* __restrict__ x, const float* __restrict__ g,
    const float* __restrict__ b, unsigned short* __restrict__ xn) {
  const int blk = blockIdx.x;
  if (blk < 3072) {
    int i = blk * 256 + threadIdx.x;      // over 786432 fvec4 groups
    const float* s; unsigned short* d; int j;
    if (i < 524288) { s = w1; d = w1b; j = i; } else { s = w2; d = w2b; j = i - 524288; }
    fvec4 v = ((const fvec4*)s)[j];
    usvec4 o = { f2b(v.x), f2b(v.y), f2b(v.z), f2b(v.w) };
    ((usvec4*)d)[j] = o;
    return;
  }
  const int lane = threadIdx.x & 63;
  const int row = (blk - 3072) * 4 + (threadIdx.x >> 6);
  const fvec4* xr = (const fvec4*)(x + (long)row * 1024);
  fvec4 v[4];
  float s = 0.f, s2 = 0.f;
  #pragma unroll
  for (int c = 0; c < 4; ++c) {
    v[c] = xr[lane + 64 * c];
    s  += v[c].x + v[c].y + v[c].z + v[c].w;
    s2 += v[c].x*v[c].x + v[c].y*v[c].y + v[c].z*v[c].z + v[c].w*v[c].w;
  }
  #pragma unroll
  for (int off = 32; off; off >>= 1) { s += __shfl_xor(s, off); s2 += __shfl_xor(s2, off); }
  float mu  = s * (1.f / 1024.f);
  float var = s2 * (1.f / 1024.f) - mu * mu;
  float rs  = rsqrtf(var + 1e-5f);
  usvec4* outr = (usvec4*)(xn + (long)row * 1024);
  #pragma unroll
  for (int c = 0; c < 4; ++c) {
    fvec4 gg = ((const fvec4*)g)[lane + 64 * c];
    fvec4 bb = ((const fvec4*)b)[lane + 64 * c];
    usvec4 o = { f2b((v[c].x - mu) * rs * gg.x + bb.x),
                 f2b((v[c].y - mu) * rs * gg.y + bb.y),
                 f2b((v[c].z - mu) * rs * gg.z + bb.z),
                 f2b((v[c].w - mu) * rs * gg.w + bb.w) };
    outr[lane + 64 * c] = o;
  }
}

// ---------------------------------------------------------------- GEMM in_proj
// C = A * Bw^T, 128x128 tile, BK=64 via dual 32-wide sub-buffers (r7 best).
// epilogue: v=silu(v+bias); n<1024 -> qkv else u (both [m][1024] bf16)
__global__ __launch_bounds__(256, 2) void gemm_in(
    const unsigned short* __restrict__ A, const unsigned short* __restrict__ Bw,
    const float* __restrict__ bias,
    unsigned short* __restrict__ out0, unsigned short* __restrict__ out1) {
  __shared__ __align__(16) unsigned short sA[2][128 * 32];
  __shared__ __align__(16) unsigned short sB[2][128 * 32];
  const int t = threadIdx.x;
  const int lane = t & 63, l15 = lane & 15, quad = lane >> 4;
  const int w = t >> 6, wm = w >> 1, wn = w & 1;
  const int m0 = blockIdx.y * 128, n0 = blockIdx.x * 128;
  const int K = 1024;

  floatx4 acc[4][4];
  const floatx4 z4 = {0.f, 0.f, 0.f, 0.f};
  #pragma unroll
  for (int i = 0; i < 4; i++)
    #pragma unroll
    for (int j = 0; j < 4; j++) acc[i][j] = z4;

  for (int kt = 0; kt < 16; ++kt) {
    const int k0 = kt << 6;
    __syncthreads();
    #pragma unroll
    for (int h = 0; h < 2; ++h) {
      #pragma unroll
      for (int c = 0; c < 2; ++c) {
        int slot = c * 256 + t;
        int row = slot >> 2, col = (slot & 3) << 3;
        async_copy16(&sA[h][slot * 8], &A[(m0 + row) * K + k0 + h * 32 + col]);
        async_copy16(&sB[h][slot * 8], &Bw[(n0 + row) * K + k0 + h * 32 + col]);
      }
    }
    __syncthreads();
    #pragma unroll
    for (int h = 0; h < 2; ++h) {
      short8 af[4], bf[4];
      #pragma unroll
      for (int mr = 0; mr < 4; mr++)
        af[mr] = *(const short8*)&sA[h][(wm * 64 + mr * 16 + l15) * 32 + quad * 8];
      #pragma unroll
      for (int nr = 0; nr < 4; nr++)
        bf[nr] = *(const short8*)&sB[h][(wn * 64 + nr * 16 + l15) * 32 + quad * 8];
      #pragma unroll
      for (int mr = 0; mr < 4; mr++)
        #pragma unroll
        for (int nr = 0; nr < 4; nr++)
          acc[mr][nr] = __builtin_amdgcn_mfma_f32_16x16x32_bf16(af[mr], bf[nr], acc[mr][nr], 0, 0, 0);
    }
  }

  #pragma unroll
  for (int mr = 0; mr < 4; mr++) {
    int gm0 = m0 + wm * 64 + mr * 16 + quad * 4;
    #pragma unroll
    for (int nr = 0; nr < 4; nr++) {
      int gn = n0 + wn * 64 + nr * 16 + l15;
      float bv = bias[gn];
      unsigned short* dst = (gn < 1024) ? (out0 + gn) : (out1 + gn - 1024);
      #pragma unroll
      for (int r = 0; r < 4; r++) {
        float v = acc[mr][nr][r] + bv;
        dst[(long)(gm0 + r) * 1024] = f2b(silu_f(v));
      }
    }
  }
}

// ---------------------------------------------------------------- GEMM out_proj
// 128x64 tile, BK=64 dual sub-buffers (r7 best). 16 K-iterations.
// outf[m][n] = acc + bias[n] + src[m][n]  (f32), N=K=1024.
__global__ __launch_bounds__(256, 2) void gemm_out(
    const unsigned short* __restrict__ A, const unsigned short* __restrict__ Bw,
    const float* __restrict__ bias, const float* __restrict__ src,
    float* __restrict__ outf) {
  __shared__ __align__(16) unsigned short sA[2][128 * 32];
  __shared__ __align__(16) unsigned short sB[2][64 * 32];
  const int t = threadIdx.x;
  const int lane = t & 63, l15 = lane & 15, quad = lane >> 4;
  const int w = t >> 6;
  const int m0 = blockIdx.y * 128, n0 = blockIdx.x * 64;

  floatx4 acc[2][4];
  const floatx4 z4 = {0.f, 0.f, 0.f, 0.f};
  #pragma unroll
  for (int i = 0; i < 2; i++)
    #pragma unroll
    for (int j = 0; j < 4; j++) acc[i][j] = z4;

  for (int kt = 0; kt < 16; ++kt) {
    const int k0 = kt << 6;
    __syncthreads();
    #pragma unroll
    for (int h = 0; h < 2; ++h) {
      #pragma unroll
      for (int c = 0; c < 2; ++c) {
        int slot = c * 256 + t;
        int row = slot >> 2, col = (slot & 3) << 3;
        async_copy16(&sA[h][slot * 8], &A[(m0 + row) * 1024 + k0 + h * 32 + col]);
      }
      { int row = t >> 2, col = (t & 3) << 3;
        async_copy16(&sB[h][t * 8], &Bw[(n0 + row) * 1024 + k0 + h * 32 + col]); }
    }
    __syncthreads();
    #pragma unroll
    for (int h = 0; h < 2; ++h) {
      short8 af[2], bf[4];
      #pragma unroll
      for (int mr = 0; mr < 2; mr++)
        af[mr] = *(const short8*)&sA[h][(w * 32 + mr * 16 + l15) * 32 + quad * 8];
      #pragma unroll
      for (int nr = 0; nr < 4; nr++)
        bf[nr] = *(const short8*)&sB[h][(nr * 16 + l15) * 32 + quad * 8];
      #pragma unroll
      for (int mr = 0; mr < 2; mr++)
        #pragma unroll
        for (int nr = 0; nr < 4; nr++)
          acc[mr][nr] = __builtin_amdgcn_mfma_f32_16x16x32_bf16(af[mr], bf[nr], acc[mr][nr], 0, 0, 0);
    }
  }

  #pragma unroll
  for (int mr = 0; mr < 2; mr++) {
    int gm0 = m0 + w * 32 + mr * 16 + quad * 4;
    #pragma unroll
    for (int nr = 0; nr < 4; nr++) {
      int gn = n0 + nr * 16 + l15;
      float bv = bias[gn];
      #pragma unroll
      for (int r = 0; r < 4; r++) {
        long idx = (long)(gm0 + r) * 1024 + gn;
        outf[idx] = acc[mr][nr][r] + bv + src[idx];
      }
    }
  }
}

// ---------------------------------------------------------------- attention v6
// r7 structure + even-qi diagonal-half skip.
// grid 512: block = (pair, bh), q-tiles {pair, 31-pair} -> 17 k-iters uniform.
// For EVEN qi, the diag tile's t-rows [64,128) are fully masked (q <= t0+63):
//   waves 2,3 skip all compute on that iter (wave-uniform branch), and the
//   producer skips staging rows >=64 of that tile (waves 0,1 never read them).
#define SKS 72
#define SVS 136
__device__ __forceinline__ void write_kv(unsigned short* sKp, unsigned short* sVp,
                                         const short8* kv, int rg, int dg, int swz0) {
  #pragma unroll
  for (int i = 0; i < 4; ++i)
    *(short8*)&sKp[(rg * 4 + i) * SKS + dg * 8] = kv[i];
  intx4 k0 = __builtin_bit_cast(intx4, kv[0]);
  intx4 k1 = __builtin_bit_cast(intx4, kv[1]);
  intx4 k2 = __builtin_bit_cast(intx4, kv[2]);
  intx4 k3 = __builtin_bit_cast(intx4, kv[3]);
  #pragma unroll
  for (int jj = 0; jj < 4; ++jj) {
    unsigned lo = __builtin_amdgcn_perm((unsigned)k1[jj], (unsigned)k0[jj], 0x05040100u);
    unsigned hi = __builtin_amdgcn_perm((unsigned)k3[jj], (unsigned)k2[jj], 0x05040100u);
    int j = 2 * jj, d = dg * 8 + j;
    int gsw = (swz0 + j) & 15;
    *(unsigned long long*)&sVp[d * SVS + gsw * 8 + (rg & 1) * 4] =
        (unsigned long long)lo | ((unsigned long long)hi << 32);
    lo = __builtin_amdgcn_perm((unsigned)k1[jj], (unsigned)k0[jj], 0x07060302u);
    hi = __builtin_amdgcn_perm((unsigned)k3[jj], (unsigned)k2[jj], 0x07060302u);
    j = 2 * jj + 1; d = dg * 8 + j;
    gsw = (swz0 + j) & 15;
    *(unsigned long long*)&sVp[d * SVS + gsw * 8 + (rg & 1) * 4] =
        (unsigned long long)lo | ((unsigned long long)hi << 32);
  }
}

__global__ __launch_bounds__(256, 2) void attn_kernel(
    const unsigned short* __restrict__ qkv, const unsigned short* __restrict__ u,
    unsigned short* __restrict__ gated) {
  __shared__ __align__(16) unsigned char smem[18432 + 2 * 17408];  // 53248 B
  unsigned short* sK   = (unsigned short*)smem;                    // [128][72]
  unsigned short* sVt0 = (unsigned short*)(smem + 18432);          // [64][136]
  unsigned short* sVt1 = (unsigned short*)(smem + 18432 + 17408);  // [64][136]
  unsigned short* sQ   = sVt1;                                     // [64][72] overlay
  float*          sR   = (float*)smem;                             // [2][64][68] epilogue

  const int t = threadIdx.x, lane = t & 63, l15 = lane & 15, quad = lane >> 4;
  const int w = t >> 6;
  const int pair = blockIdx.x >> 5, bh = blockIdx.x & 31;
  const int b = bh >> 4, h = bh & 15;
  const long base = (long)b * 1024 + h * 64;   // + s*2048
  const int rg = t >> 3, dg = t & 7;           // staging roles
  const int swz0 = (rg >> 1) + dg;             // sVt write swizzle base
  const int addr_lo = 4 * (l15 + 32 * (quad & 1));
  const int addr_hi = addr_lo + 64;
  const bool qhi = quad >= 2;                  // selects source m-tile
  const int vswz = w * 4 + quad + (l15 & 7) + (l15 >> 3);  // sVt read swizzle base
  const floatx4 z4 = {0.f, 0.f, 0.f, 0.f};

  for (int half = 0; half < 2; ++half) {
    const int qi = half ? (31 - pair) : pair;
    const int q0 = qi * 64;
    const int nkt = (qi >> 1) + 1;
    const bool evq = !(qi & 1);                // even qi: diag tile upper half dead

    if (half) __syncthreads();               // prior epilogue reads done
    // ---- stage Q (into sVt1 overlay), pull B-frags ----
    #pragma unroll
    for (int c = 0; c < 2; ++c) {
      int slot = c * 256 + t, row = slot >> 3, cg = slot & 7;
      *(short8*)&sQ[row * SKS + cg * 8] =
          *(const short8*)&qkv[base + (long)(q0 + row) * 2048 + cg * 8];
    }
    __syncthreads();
    short8 qf[4][2];
    #pragma unroll
    for (int nt = 0; nt < 4; nt++)
      #pragma unroll
      for (int ks = 0; ks < 2; ks++)
        qf[nt][ks] = *(const short8*)&sQ[(nt * 16 + l15) * SKS + ks * 32 + quad * 8];
    // ---- prologue: stage K-tile 0 (sK + sVt0; disjoint from sQ) ----
    short8 kv[4];
    #pragma unroll
    for (int i = 0; i < 4; ++i)
      kv[i] = *(const short8*)&qkv[base + (long)(rg * 4 + i) * 2048 + dg * 8];
    write_kv(sK, sVt0, kv, rg, dg, swz0);

    floatx4 oacc[4][4];
    #pragma unroll
    for (int i = 0; i < 4; i++)
      #pragma unroll
      for (int j = 0; j < 4; j++) oacc[i][j] = z4;

    for (int kt = 0; kt < nkt; ++kt) {
      unsigned short* sVtC = (kt & 1) ? sVt1 : sVt0;
      unsigned short* sVtN = (kt & 1) ? sVt0 : sVt1;
      __syncthreads();                       // T1: staging of tile kt visible
      const bool more = (kt + 1 < nkt);
      // next tile is the diag tile of an even qi -> its rows >=64 are dead
      const bool stage_half = evq && (kt + 2 == nkt);
      const bool do_stage = more && (!stage_half || rg < 16);
      if (do_stage) {
        const long nb = base + (long)((kt + 1) * 128) * 2048;
        #pragma unroll
        for (int i = 0; i < 4; ++i)
          kv[i] = *(const short8*)&qkv[nb + (long)(rg * 4 + i) * 2048 + dg * 8];
      }
      const bool diag = (kt == nkt - 1);
      const bool skipw = diag && evq && (w >= 2);   // wave-uniform dead-work skip
      short8 kf[2][2];
      if (!skipw) {
        #pragma unroll
        for (int mt = 0; mt < 2; mt++)
          #pragma unroll
          for (int ks = 0; ks < 2; ks++)
            kf[mt][ks] = *(const short8*)&sK[(w * 32 + mt * 16 + l15) * SKS + ks * 32 + quad * 8];
      }
      __syncthreads();                       // T2: all kf reads done -> sK writable
      if (!skipw) {
        // ---- S^T = K Q^T : wave owns t-rows [w*32, w*32+32) ----
        floatx4 sacc[2][4];
        #pragma unroll
        for (int i = 0; i < 2; i++)
          #pragma unroll
          for (int j = 0; j < 4; j++) sacc[i][j] = z4;
        #pragma unroll
        for (int ks = 0; ks < 2; ++ks)
          #pragma unroll
          for (int mt = 0; mt < 2; mt++)
            #pragma unroll
            for (int nt = 0; nt < 4; nt++)
              sacc[mt][nt] = __builtin_amdgcn_mfma_f32_16x16x32_bf16(
                  kf[mt][ks], qf[nt][ks], sacc[mt][nt], 0, 0, 0);
        // ---- scale, silu, mask (diag only); pack bf16 pairs ----
        const int tw = kt * 128 + w * 32;
        unsigned p0[2][4], p1[2][4];
        #pragma unroll
        for (int mt = 0; mt < 2; mt++)
          #pragma unroll
          for (int nt = 0; nt < 4; nt++) {
            float v[4];
            if (diag) {
              int qq = q0 + nt * 16 + l15;
              #pragma unroll
              for (int r = 0; r < 4; r++) {
                int tt = tw + mt * 16 + quad * 4 + r;
                float x = silu_f(sacc[mt][nt][r] * 0.125f);
                v[r] = (qq < tt) ? 0.f : x;
              }
            } else {
              #pragma unroll
              for (int r = 0; r < 4; r++) v[r] = silu_f(sacc[mt][nt][r] * 0.125f);
            }
            p0[mt][nt] = __builtin_amdgcn_perm(__builtin_bit_cast(unsigned, v[1]),
                                               __builtin_bit_cast(unsigned, v[0]), 0x07060302u);
            p1[mt][nt] = __builtin_amdgcn_perm(__builtin_bit_cast(unsigned, v[3]),
                                               __builtin_bit_cast(unsigned, v[2]), 0x07060302u);
          }
        // ---- PV: O_partial[q][d] += P[q][t-slice] * V[t-slice][d] ----
        short8 vb[4];
        #pragma unroll
        for (int dt = 0; dt < 4; dt++)
          vb[dt] = *(const short8*)&sVtC[(dt * 16 + l15) * SVS + ((vswz + 2 * dt) & 15) * 8];
        #pragma unroll
        for (int qt = 0; qt < 4; qt++) {
          intx4 pa;
          #pragma unroll
          for (int jj = 0; jj < 4; jj++) {
            int addr = (jj >> 1) ? addr_hi : addr_lo;
            int lo, hi;
            if (jj & 1) {
              lo = __builtin_amdgcn_ds_bpermute(addr, (int)p1[0][qt]);
              hi = __builtin_amdgcn_ds_bpermute(addr, (int)p1[1][qt]);
            } else {
              lo = __builtin_amdgcn_ds_bpermute(addr, (int)p0[0][qt]);
              hi = __builtin_amdgcn_ds_bpermute(addr, (int)p0[1][qt]);
            }
            pa[jj] = qhi ? hi : lo;
          }
          short8 paf = __builtin_bit_cast(short8, pa);
          #pragma unroll
          for (int dt = 0; dt < 4; dt++)
            oacc[qt][dt] = __builtin_amdgcn_mfma_f32_16x16x32_bf16(paf, vb[dt], oacc[qt][dt], 0, 0, 0);
        }
      }
      // ---- stage tile kt+1 (writes overlap nothing being read) ----
      if (do_stage) write_kv(sK, sVtN, kv, rg, dg, swz0);
    }

    // ---- epilogue: cross-wave partial-O reduce, gated = O*u ----
    __syncthreads();                         // E1: all k-loop LDS reads done
    float* plane = sR + (w & 1) * 4352;      // [64][68]
    if (w < 2) {
      #pragma unroll
      for (int qt = 0; qt < 4; qt++)
        #pragma unroll
        for (int dt = 0; dt < 4; dt++)
          #pragma unroll
          for (int r = 0; r < 4; r++)
            plane[(qt * 16 + quad * 4 + r) * 68 + dt * 16 + l15] = oacc[qt][dt][r];
    }
    __syncthreads();                         // E2
    if (w >= 2) {
      #pragma unroll
      for (int qt = 0; qt < 4; qt++)
        #pragma unroll
        for (int dt = 0; dt < 4; dt++)
          #pragma unroll
          for (int r = 0; r < 4; r++)
            plane[(qt * 16 + quad * 4 + r) * 68 + dt * 16 + l15] += oacc[qt][dt][r];
    }
    __syncthreads();                         // E3
    {
      const int erow = t >> 2, edg = t & 3;
      const long grow = (long)(q0 + erow) * 2048 + base + edg * 16;
      short8 u0 = *(const short8*)&u[grow];
      short8 u1 = *(const short8*)&u[grow + 8];
      const float* r0p = sR + erow * 68 + edg * 16;
      const float* r1p = r0p + 4352;
      float o[16];
      #pragma unroll
      for (int c = 0; c < 4; c++) {
        fvec4 a = ((const fvec4*)r0p)[c];
        fvec4 bsum = ((const fvec4*)r1p)[c];
        o[4*c+0] = a.x + bsum.x; o[4*c+1] = a.y + bsum.y;
        o[4*c+2] = a.z + bsum.z; o[4*c+3] = a.w + bsum.w;
      }
      short8 g0, g1;
      #pragma unroll
      for (int j = 0; j < 8; ++j) {
        g0[j] = (short)f2b(o[j]     * b2f((unsigned short)u0[j]));
        g1[j] = (short)f2b(o[j + 8] * b2f((unsigned short)u1[j]));
      }
      *(short8*)&gated[grow]     = g0;
      *(short8*)&gated[grow + 8] = g1;
    }
  }
}

// ---------------------------------------------------------------- launch
extern "C" void kernel_launch(void* const* d_in, const int* in_sizes, int n_in,
                              void* d_out, int out_size, void* d_ws, size_t ws_size,
                              hipStream_t stream) {
  const float* src = (const float*)d_in[0];
  // d_in[1] = src_mask: tril, causality handled structurally
  const float* w1  = (const float*)d_in[2];
  const float* b1  = (const float*)d_in[3];
  const float* w2  = (const float*)d_in[4];
  const float* b2  = (const float*)d_in[5];
  const float* lng = (const float*)d_in[6];
  const float* lnb = (const float*)d_in[7];
  float* out = (float*)d_out;

  char* ws = (char*)d_ws;
  unsigned short* xn    = (unsigned short*)(ws + 0);          // 4096x1024 bf16
  unsigned short* qkv   = (unsigned short*)(ws + 8388608);    // 4096x1024 bf16
  unsigned short* uu    = (unsigned short*)(ws + 16777216);   // 4096x1024 bf16
  unsigned short* gated = (unsigned short*)(ws + 25165824);   // 4096x1024 bf16
  unsigned short* w1b   = (unsigned short*)(ws + 33554432);   // 2048x1024 bf16
  unsigned short* w2b   = (unsigned short*)(ws + 37748736);   // 1024x1024 bf16

  prep_kernel<<<4096, 256, 0, stream>>>(w1, w1b, w2, w2b, src, lng, lnb, xn);
  gemm_in<<<dim3(16, 32), 256, 0, stream>>>(xn, w1b, b1, qkv, uu);
  attn_kernel<<<512, 256, 0, stream>>>(qkv, uu, gated);
  gemm_out<<<dim3(16, 32), 256, 0, stream>>>(gated, w2b, b2, src, out);
}